// Round 1
// baseline (557.229 us; speedup 1.0000x reference)
//
#include <hip/hip_runtime.h>

// ChebConv K=3 GCN on MI355X.
// N=100000 nodes, E=3200000 edges, F=16 in-feats, 2 out-feats.
// Structure: deg histogram -> norm -> scatter prop x2 -> fused X2+matmul+relu.
// Round 1: atomic-scatter baseline. thread=(edge,feat) so each 16-lane group
// does one 64B gather line from Y[src] and one 64B atomic line into P[dst].

#define NN 100000
#define NE 3200000
#define F  16

__global__ void k_deg(const int* __restrict__ dst, int* __restrict__ deg) {
    int e = blockIdx.x * blockDim.x + threadIdx.x;
    if (e < NE) atomicAdd(&deg[dst[e]], 1);
}

__global__ void k_norm_y(const int* __restrict__ deg, float* __restrict__ norm,
                         const float* __restrict__ X0, float* __restrict__ Y) {
    int n = blockIdx.x * blockDim.x + threadIdx.x;
    if (n >= NN) return;
    int d = deg[n];
    float nv = rsqrtf((float)(d < 1 ? 1 : d));
    norm[n] = nv;
    const float4* Xv = (const float4*)(X0 + (size_t)n * F);
    float4* Yv = (float4*)(Y + (size_t)n * F);
#pragma unroll
    for (int i = 0; i < 4; ++i) {
        float4 x = Xv[i];
        Yv[i] = make_float4(x.x * nv, x.y * nv, x.z * nv, x.w * nv);
    }
}

// One thread per (edge, feat). 16 consecutive lanes share one edge:
// coalesced 64B read of Y[src] row, 16 atomics into one 64B line of P[dst].
__global__ void k_scatter(const int* __restrict__ src, const int* __restrict__ dst,
                          const float* __restrict__ Y, float* __restrict__ P) {
    int tid = blockIdx.x * blockDim.x + threadIdx.x;  // NE*F = 51.2M < 2^31
    if (tid >= NE * F) return;
    int e = tid >> 4;
    int f = tid & 15;
    int s = src[e];
    int d = dst[e];
    atomicAdd(&P[(size_t)d * F + f], Y[(size_t)s * F + f]);
}

// X1 = -r*(norm*P0) + (r-1)*X0 ; Y <- norm*X1 (for the second scatter pass)
__global__ void k_x1(const float* __restrict__ norm, const float* __restrict__ P,
                     const float* __restrict__ X0, const float* __restrict__ lm,
                     float* __restrict__ X1, float* __restrict__ Y) {
    int n = blockIdx.x * blockDim.x + threadIdx.x;
    if (n >= NN) return;
    float r = 2.0f / lm[0];
    float a = -r, b = r - 1.0f;
    float nv = norm[n];
    const float4* Pv = (const float4*)(P + (size_t)n * F);
    const float4* Xv = (const float4*)(X0 + (size_t)n * F);
    float4* X1v = (float4*)(X1 + (size_t)n * F);
    float4* Yv = (float4*)(Y + (size_t)n * F);
#pragma unroll
    for (int i = 0; i < 4; ++i) {
        float4 p = Pv[i];
        float4 x = Xv[i];
        float4 x1;
        x1.x = a * (nv * p.x) + b * x.x;
        x1.y = a * (nv * p.y) + b * x.y;
        x1.z = a * (nv * p.z) + b * x.z;
        x1.w = a * (nv * p.w) + b * x.w;
        X1v[i] = x1;
        Yv[i] = make_float4(x1.x * nv, x1.y * nv, x1.z * nv, x1.w * nv);
    }
}

// X2 = -2r*(norm*P1) + 2(r-1)*X1 - X0 ; out = relu([X0|X1|X2] @ W^T)
__global__ void k_out(const float* __restrict__ norm, const float* __restrict__ P,
                      const float* __restrict__ X0, const float* __restrict__ X1,
                      const float* __restrict__ W, const float* __restrict__ lm,
                      float* __restrict__ out) {
    __shared__ float Ws[96];
    if (threadIdx.x < 96) Ws[threadIdx.x] = W[threadIdx.x];
    __syncthreads();
    int n = blockIdx.x * blockDim.x + threadIdx.x;
    if (n >= NN) return;
    float r = 2.0f / lm[0];
    float c1 = -2.0f * r;
    float c2 = 2.0f * (r - 1.0f);
    float nv = norm[n];
    const float* x0 = X0 + (size_t)n * F;
    const float* x1 = X1 + (size_t)n * F;
    const float* p  = P + (size_t)n * F;
    float acc0 = 0.f, acc1 = 0.f;
#pragma unroll
    for (int f = 0; f < F; ++f) {
        float v0 = x0[f];
        float v1 = x1[f];
        float v2 = c1 * (nv * p[f]) + c2 * v1 - v0;
        acc0 += Ws[f] * v0 + Ws[16 + f] * v1 + Ws[32 + f] * v2;
        acc1 += Ws[48 + f] * v0 + Ws[64 + f] * v1 + Ws[80 + f] * v2;
    }
    out[(size_t)n * 2 + 0] = fmaxf(acc0, 0.f);
    out[(size_t)n * 2 + 1] = fmaxf(acc1, 0.f);
}

extern "C" void kernel_launch(void* const* d_in, const int* in_sizes, int n_in,
                              void* d_out, int out_size, void* d_ws, size_t ws_size,
                              hipStream_t stream) {
    const float* in_feat = (const float*)d_in[0];
    const float* W       = (const float*)d_in[1];
    const int*   src     = (const int*)d_in[2];
    const int*   dst     = (const int*)d_in[3];
    const float* lm      = (const float*)d_in[4];
    float* out = (float*)d_out;

    // Workspace layout (floats): deg[NN](int) | norm[NN] | Y[NN*F] | P[NN*F] | X1[NN*F]
    float* ws   = (float*)d_ws;
    int*   deg  = (int*)ws;
    float* norm = ws + NN;
    float* Y    = ws + 2 * NN;
    float* P    = ws + 2 * NN + (size_t)NN * F;
    float* X1   = ws + 2 * NN + (size_t)2 * NN * F;

    const int B = 256;
    hipMemsetAsync(deg, 0, NN * sizeof(int), stream);
    k_deg<<<(NE + B - 1) / B, B, 0, stream>>>(dst, deg);
    k_norm_y<<<(NN + B - 1) / B, B, 0, stream>>>(deg, norm, in_feat, Y);

    hipMemsetAsync(P, 0, (size_t)NN * F * sizeof(float), stream);
    k_scatter<<<(NE * F) / B, B, 0, stream>>>(src, dst, Y, P);
    k_x1<<<(NN + B - 1) / B, B, 0, stream>>>(norm, P, in_feat, lm, X1, Y);

    hipMemsetAsync(P, 0, (size_t)NN * F * sizeof(float), stream);
    k_scatter<<<(NE * F) / B, B, 0, stream>>>(src, dst, Y, P);
    k_out<<<(NN + B - 1) / B, B, 0, stream>>>(norm, P, in_feat, X1, W, lm, out);
}